// Round 9
// baseline (271.130 us; speedup 1.0000x reference)
//
#include <hip/hip_runtime.h>

#define TT 128

// LIF constants
#define DECAY_U 0.75f
#define DECAY_V 0.96875f
#define THETA   5120.0f
#define POOLW   88.0f

__device__ __forceinline__ void lif_step(float xt, float& u, float& v, int& refc, float& s) {
    u = __fadd_rn(__fmul_rn(u, DECAY_U), __fmul_rn(xt, 64.0f));
    float vn = __fadd_rn(__fmul_rn(v, DECAY_V), u);
    v = refc ? 0.0f : vn;
    s = (v >= THETA) ? 1.0f : 0.0f;
    if (s > 0.f) { refc = 1; v = 0.f; }
    else         { refc = refc > 0 ? refc - 1 : 0; }
}

// Serial LIF over an LDS column: col[t*stride], t=0..127.
__device__ __forceinline__ void lif_seq_lds(float* col, int stride) {
    float u = 0.f, v = 0.f;
    int refc = 0;
    #pragma unroll 16
    for (int t = 0; t < TT; ++t) {
        float s;
        lif_step(col[t * stride], u, v, refc, s);
        col[t * stride] = s;
    }
}

// ---------------- Weight transpose: [oc][ck] -> [ck][oc] (oc contiguous) ----------
__global__ void wtrans_k(const float* __restrict__ w1, const float* __restrict__ w2,
                         float* __restrict__ wTg1, float* __restrict__ wTg2) {
    int i = blockIdx.x * 256 + threadIdx.x;
    if (i < 800) {
        int oc = i & 15, ck = i >> 4;          // ck = c*25 + tap
        wTg1[ck*16 + oc] = w1[oc*50 + ck];
    }
    if (i < 4608) {
        int oc = i & 31, ck = i >> 5;          // ck = c*9 + tap
        wTg2[ck*32 + oc] = w2[oc*144 + ck];
    }
}

// ---------------- L1: sum_pool(x,4)*88 + LIF -> s1 fp32 ----------------
__global__ void pool1_lif_k(const float* __restrict__ x, float* __restrict__ s1) {
    __shared__ float sb[TT][3];
    int t = threadIdx.x & 127, pos = threadIdx.x >> 7;
    int n = blockIdx.x * 2 + pos;
    int px = n & 31, py = (n >> 5) & 31, c = (n >> 10) & 1, b = n >> 11;
    const float* base = x + (size_t)((((b*2 + c)*128 + py*4)*128) + px*4) * 128 + t;
    float s = 0.f;
    #pragma unroll
    for (int dy = 0; dy < 4; ++dy)
        #pragma unroll
        for (int dx = 0; dx < 4; ++dx)
            s += base[(dy*128 + dx) * 128];
    sb[t][pos] = s * POOLW;
    __syncthreads();
    if (threadIdx.x < 2) lif_seq_lds(&sb[0][threadIdx.x], 3);
    __syncthreads();
    s1[(size_t)n * TT + t] = sb[t][pos];
}

// ---------------- pack s1 (2 c bits) -> pk1 [8][1024][128] uint8 ----------------
__global__ void pack1_k(const float* __restrict__ s1, unsigned char* __restrict__ pk1) {
    int id = blockIdx.x * 256 + threadIdx.x;     // 1,048,576
    int t = id & 127;
    int pos = id >> 7;
    int b = pos >> 10, rem = pos & 1023;
    const float* p0 = s1 + (size_t)(b*2) * 131072 + rem * 128 + t;
    unsigned int v = (p0[0] > 0.5f ? 1u : 0u) | (p0[131072] > 0.5f ? 2u : 0u);
    pk1[id] = (unsigned char)v;
}

// ---------------- L2: conv1 5x5 SAME 2->16 (delayed, packed in/out) + LIF ---------
// block = 2 pos x 16 oc x 128 t; thread = (pos, ocg[8 oc], t2[2 t]).
__global__ __launch_bounds__(256) void conv1_lif_pack_k(const unsigned char* __restrict__ pk1,
                                                        const float* __restrict__ wTg1,
                                                        unsigned short* __restrict__ pk2) {
    __shared__ float sb[TT][33];   // [t][nl], nl = oc*2 + pos
    int tid = threadIdx.x;
    int t2  = tid & 63;
    int ocg = (tid >> 6) & 1;      // wave-uniform
    int pos = tid >> 7;
    int n = blockIdx.x * 2 + pos;
    int px = n & 31, py = (n >> 5) & 31, b = n >> 10;
    const unsigned char* pp = pk1 + (size_t)b * 131072;

    float acc[2][8];
    #pragma unroll
    for (int i = 0; i < 2; ++i)
        #pragma unroll
        for (int k = 0; k < 8; ++k) acc[i][k] = 0.f;

    #pragma unroll
    for (int ky = 0; ky < 5; ++ky) {
        int iy = py + ky - 2;
        unsigned int row[5][2];
        #pragma unroll
        for (int kx = 0; kx < 5; ++kx) {
            int ix = px + kx - 2;
            bool vs = ((unsigned)iy < 32u) && ((unsigned)ix < 32u);
            int iyc = vs ? iy : 0, ixc = vs ? ix : 0;
            const unsigned char* q = pp + (iyc*32 + ixc) * 128;
            #pragma unroll
            for (int i = 0; i < 2; ++i) {
                int t = t2*2 + i;
                bool v = vs && (t > 0);
                unsigned int w = q[v ? t-1 : 0];
                row[kx][i] = v ? w : 0u;
            }
        }
        #pragma unroll
        for (int kx = 0; kx < 5; ++kx) {
            const float4* wv0 = (const float4*)&wTg1[(ky*5 + kx) * 16 + ocg*8];
            const float4* wv1 = (const float4*)&wTg1[(25 + ky*5 + kx) * 16 + ocg*8];
            float4 a0 = wv0[0], a1 = wv0[1];
            float4 c0 = wv1[0], c1 = wv1[1];
            #pragma unroll
            for (int i = 0; i < 2; ++i) {
                float x0 = (float)(row[kx][i] & 1u);
                float x1 = (float)((row[kx][i] >> 1) & 1u);
                acc[i][0] = fmaf(a0.x, x0, acc[i][0]);
                acc[i][1] = fmaf(a0.y, x0, acc[i][1]);
                acc[i][2] = fmaf(a0.z, x0, acc[i][2]);
                acc[i][3] = fmaf(a0.w, x0, acc[i][3]);
                acc[i][4] = fmaf(a1.x, x0, acc[i][4]);
                acc[i][5] = fmaf(a1.y, x0, acc[i][5]);
                acc[i][6] = fmaf(a1.z, x0, acc[i][6]);
                acc[i][7] = fmaf(a1.w, x0, acc[i][7]);
                acc[i][0] = fmaf(c0.x, x1, acc[i][0]);
                acc[i][1] = fmaf(c0.y, x1, acc[i][1]);
                acc[i][2] = fmaf(c0.z, x1, acc[i][2]);
                acc[i][3] = fmaf(c0.w, x1, acc[i][3]);
                acc[i][4] = fmaf(c1.x, x1, acc[i][4]);
                acc[i][5] = fmaf(c1.y, x1, acc[i][5]);
                acc[i][6] = fmaf(c1.z, x1, acc[i][6]);
                acc[i][7] = fmaf(c1.w, x1, acc[i][7]);
            }
        }
    }
    #pragma unroll
    for (int i = 0; i < 2; ++i) {
        int t = t2*2 + i;
        #pragma unroll
        for (int k = 0; k < 8; ++k)
            sb[t][(ocg*8 + k)*2 + pos] = acc[i][k];
    }
    __syncthreads();
    if (tid < 32) lif_seq_lds(&sb[0][tid], 33);
    __syncthreads();
    if (tid < 128) {
        int t = tid;
        #pragma unroll
        for (int p2 = 0; p2 < 2; ++p2) {
            unsigned int w = 0;
            #pragma unroll
            for (int oc = 0; oc < 16; ++oc)
                w |= (sb[t][oc*2 + p2] > 0.5f ? 1u : 0u) << oc;
            int n2 = blockIdx.x * 2 + p2;
            pk2[(size_t)(n2 >> 10) * 131072 + (size_t)(n2 & 1023) * 128 + t] = (unsigned short)w;
        }
    }
}

// ---------------- L3: sum_pool(2)*88 (delayed, packed in) + LIF + pack -> pk3 -----
// block = 1 position x 16 c x 128 t
__global__ __launch_bounds__(256) void pool2pack_k(const unsigned short* __restrict__ pk2,
                                                   unsigned short* __restrict__ pk3) {
    __shared__ float sb[TT][17];
    int tid = threadIdx.x;
    int t = tid & 127, half = tid >> 7;
    int pos = blockIdx.x & 255, b = blockIdx.x >> 8;
    int px = pos & 15, py = pos >> 4;
    unsigned int w0 = 0, w1 = 0, w2 = 0, w3 = 0;
    if (t > 0) {
        const unsigned short* q = pk2 + (size_t)b * 131072 + (size_t)(py*2*32 + px*2) * 128 + (t - 1);
        w0 = q[0]; w1 = q[128]; w2 = q[32*128]; w3 = q[33*128];
    }
    #pragma unroll
    for (int j = 0; j < 8; ++j) {
        int c = half*8 + j;
        int cnt = ((w0 >> c) & 1) + ((w1 >> c) & 1) + ((w2 >> c) & 1) + ((w3 >> c) & 1);
        sb[t][c] = POOLW * (float)cnt;
    }
    __syncthreads();
    if (tid < 16) lif_seq_lds(&sb[0][tid], 17);
    __syncthreads();
    if (tid < 128) {
        unsigned int w = 0;
        #pragma unroll
        for (int c = 0; c < 16; ++c)
            w |= (sb[tid][c] > 0.5f ? 1u : 0u) << c;
        pk3[(size_t)b * 32768 + (size_t)pos * 128 + tid] = (unsigned short)w;
    }
}

// ---------------- L4: conv2 3x3 SAME 16->32 (delayed, packed in/out) + LIF --------
// block = 1 position x 32 oc x 128 t; thread = (ocg[8 oc], t2[2 t]).
__global__ __launch_bounds__(256) void conv2_lif_pack_k(const unsigned short* __restrict__ pk3,
                                                        const float* __restrict__ wTg2,
                                                        unsigned int* __restrict__ pk4) {
    __shared__ float sb[TT][33];   // [t][oc]
    int tid = threadIdx.x;
    int t2  = tid & 63;
    int ocg = tid >> 6;            // 0..3, wave-uniform
    int pos = blockIdx.x & 255, b = blockIdx.x >> 8;
    int px = pos & 15, py = pos >> 4;
    const unsigned short* pp = pk3 + (size_t)b * 32768;

    unsigned int pkv[9][2];
    #pragma unroll
    for (int ky = 0; ky < 3; ++ky) {
        int iy = py + ky - 1;
        #pragma unroll
        for (int kx = 0; kx < 3; ++kx) {
            int ix = px + kx - 1;
            bool vs = ((unsigned)iy < 16u) && ((unsigned)ix < 16u);
            int iyc = vs ? iy : 0, ixc = vs ? ix : 0;
            const unsigned short* q = pp + (iyc*16 + ixc) * 128;
            #pragma unroll
            for (int i = 0; i < 2; ++i) {
                int t = t2*2 + i;
                bool v = vs && (t > 0);
                unsigned int w = q[v ? t-1 : 0];
                pkv[ky*3 + kx][i] = v ? w : 0u;
            }
        }
    }

    float acc[2][8];
    #pragma unroll
    for (int i = 0; i < 2; ++i)
        #pragma unroll
        for (int k = 0; k < 8; ++k) acc[i][k] = 0.f;

    #pragma unroll
    for (int c = 0; c < 16; ++c) {
        #pragma unroll
        for (int tap = 0; tap < 9; ++tap) {
            const float4* wv = (const float4*)&wTg2[(c*9 + tap) * 32 + ocg*8];
            float4 w0 = wv[0], w1 = wv[1];
            #pragma unroll
            for (int i = 0; i < 2; ++i) {
                float xc = (float)((pkv[tap][i] >> c) & 1u);
                acc[i][0] = fmaf(w0.x, xc, acc[i][0]);
                acc[i][1] = fmaf(w0.y, xc, acc[i][1]);
                acc[i][2] = fmaf(w0.z, xc, acc[i][2]);
                acc[i][3] = fmaf(w0.w, xc, acc[i][3]);
                acc[i][4] = fmaf(w1.x, xc, acc[i][4]);
                acc[i][5] = fmaf(w1.y, xc, acc[i][5]);
                acc[i][6] = fmaf(w1.z, xc, acc[i][6]);
                acc[i][7] = fmaf(w1.w, xc, acc[i][7]);
            }
        }
    }
    #pragma unroll
    for (int i = 0; i < 2; ++i) {
        int t = t2*2 + i;
        #pragma unroll
        for (int k = 0; k < 8; ++k)
            sb[t][ocg*8 + k] = acc[i][k];
    }
    __syncthreads();
    if (tid < 32) lif_seq_lds(&sb[0][tid], 33);
    __syncthreads();
    if (tid < 128) {
        unsigned int w = 0;
        #pragma unroll
        for (int oc = 0; oc < 32; ++oc)
            w |= (sb[tid][oc] > 0.5f ? 1u : 0u) << oc;
        pk4[(size_t)b * 32768 + (size_t)pos * 128 + tid] = w;
    }
}

// ---------------- L5: sum_pool(2)*88 (delayed, packed in) + LIF -> s5 fp32 --------
__global__ void pool3_lif_k(const unsigned int* __restrict__ pk4, float* __restrict__ s5) {
    __shared__ float sb[TT][3];
    int t = threadIdx.x & 127, pos = threadIdx.x >> 7;
    int n = blockIdx.x * 2 + pos;
    int px = n & 7, py = (n >> 3) & 7, c = (n >> 6) & 31, b = n >> 11;
    float acc = 0.f;
    if (t > 0) {
        const unsigned int* q = pk4 + (size_t)b * 32768 + (size_t)(py*2*16 + px*2) * 128 + (t - 1);
        unsigned int w0 = q[0], w1 = q[128], w2 = q[16*128], w3 = q[17*128];
        int cnt = ((w0 >> c) & 1) + ((w1 >> c) & 1) + ((w2 >> c) & 1) + ((w3 >> c) & 1);
        acc = POOLW * (float)cnt;
    }
    sb[t][pos] = acc;
    __syncthreads();
    if (threadIdx.x < 2) lif_seq_lds(&sb[0][threadIdx.x], 3);
    __syncthreads();
    s5[(size_t)n * TT + t] = sb[t][pos];
}

// ---------------- L6: fc1 tiled K-split GEMM ----------------
__global__ __launch_bounds__(256) void fc1_gemm_k(const float* __restrict__ s5,
                                                  const float* __restrict__ wf1,
                                                  float* __restrict__ part) {
    __shared__ float WT[64][68];
    __shared__ float ST[64][68];
    int bid = blockIdx.x;
    int kc = bid & 7;
    int ot = (bid >> 3) & 7;
    int tt = (bid >> 6) & 1;
    int b  = bid >> 7;
    int tid = threadIdx.x;
    int oo = tid >> 4;
    int to = tid & 15;

    const float* wbase = wf1 + (size_t)(ot*64) * 2048 + kc*256;
    const float* sbase = s5 + (size_t)b * 262144 + (size_t)(kc*256) * 128;

    float acc[4][4];
    #pragma unroll
    for (int i = 0; i < 4; ++i)
        #pragma unroll
        for (int j = 0; j < 4; ++j) acc[i][j] = 0.f;

    for (int ks = 0; ks < 4; ++ks) {
        __syncthreads();
        #pragma unroll
        for (int i = 0; i < 16; ++i) {
            int e = tid + 256*i;
            int o = e >> 6, f = e & 63;
            WT[f][o] = wbase[(size_t)o * 2048 + ks*64 + f];
        }
        #pragma unroll
        for (int i = 0; i < 16; ++i) {
            int e = tid + 256*i;
            int f = e >> 6, tl = e & 63;
            int tsrc = tt*64 + tl - 1;
            ST[f][tl] = (tsrc < 0) ? 0.f : sbase[(size_t)f * 128 + ks*64*128 + tsrc];
        }
        __syncthreads();
        #pragma unroll 4
        for (int k = 0; k < 64; ++k) {
            float4 a = *(const float4*)&WT[k][oo*4];
            float4 s = *(const float4*)&ST[k][to*4];
            acc[0][0] = fmaf(a.x, s.x, acc[0][0]);
            acc[0][1] = fmaf(a.x, s.y, acc[0][1]);
            acc[0][2] = fmaf(a.x, s.z, acc[0][2]);
            acc[0][3] = fmaf(a.x, s.w, acc[0][3]);
            acc[1][0] = fmaf(a.y, s.x, acc[1][0]);
            acc[1][1] = fmaf(a.y, s.y, acc[1][1]);
            acc[1][2] = fmaf(a.y, s.z, acc[1][2]);
            acc[1][3] = fmaf(a.y, s.w, acc[1][3]);
            acc[2][0] = fmaf(a.z, s.x, acc[2][0]);
            acc[2][1] = fmaf(a.z, s.y, acc[2][1]);
            acc[2][2] = fmaf(a.z, s.z, acc[2][2]);
            acc[2][3] = fmaf(a.z, s.w, acc[2][3]);
            acc[3][0] = fmaf(a.w, s.x, acc[3][0]);
            acc[3][1] = fmaf(a.w, s.y, acc[3][1]);
            acc[3][2] = fmaf(a.w, s.z, acc[3][2]);
            acc[3][3] = fmaf(a.w, s.w, acc[3][3]);
        }
    }
    float* pb = part + (size_t)kc * 524288 + (size_t)b * 65536
              + (size_t)(ot*64 + oo*4) * 128 + tt*64 + to*4;
    #pragma unroll
    for (int i = 0; i < 4; ++i)
        #pragma unroll
        for (int j = 0; j < 4; ++j)
            pb[(size_t)i * 128 + j] = acc[i][j];
}

// ---------------- L6b: sum 8 K-chunks (fixed order) + LIF -> s6 ----------------
__global__ void fc1_reduce_lif_k(const float* __restrict__ part, float* __restrict__ s6) {
    __shared__ float sb[TT][3];
    int t = threadIdx.x & 127, pos = threadIdx.x >> 7;
    int n = blockIdx.x * 2 + pos;
    float s = 0.f;
    #pragma unroll
    for (int kc = 0; kc < 8; ++kc)
        s += part[(size_t)kc * 524288 + (size_t)n * 128 + t];
    sb[t][pos] = s;
    __syncthreads();
    if (threadIdx.x < 2) lif_seq_lds(&sb[0][threadIdx.x], 3);
    __syncthreads();
    s6[(size_t)n * TT + t] = sb[t][pos];
}

// ---------------- L7: fc2 512->11 (delayed) + LIF + final shift -> out ----------
__global__ void fc2_lif_k(const float* __restrict__ s6, const float* __restrict__ wf2,
                          float* __restrict__ out) {
    __shared__ float sb[TT];
    int t = threadIdx.x;
    int o = blockIdx.x % 11, b = blockIdx.x / 11;
    float acc = 0.f;
    if (t > 0) {
        const float* sp = s6 + (size_t)b * 65536 + (t - 1);
        const float* wp = wf2 + o * 512;
        for (int f = 0; f < 512; f += 4) {
            float4 w = *(const float4*)&wp[f];
            acc = fmaf(w.x, sp[(size_t)f * 128], acc);
            acc = fmaf(w.y, sp[(size_t)(f+1) * 128], acc);
            acc = fmaf(w.z, sp[(size_t)(f+2) * 128], acc);
            acc = fmaf(w.w, sp[(size_t)(f+3) * 128], acc);
        }
    }
    sb[t] = acc;
    __syncthreads();
    if (t == 0) lif_seq_lds(sb, 1);
    __syncthreads();
    float* q = out + (size_t)(b*11 + o) * TT;
    if (t == 0) q[0] = 0.f;
    if (t < TT - 1) q[t + 1] = sb[t];
}

extern "C" void kernel_launch(void* const* d_in, const int* in_sizes, int n_in,
                              void* d_out, int out_size, void* d_ws, size_t ws_size,
                              hipStream_t stream) {
    const float* x   = (const float*)d_in[0];
    const float* w1  = (const float*)d_in[1];
    const float* w2  = (const float*)d_in[2];
    const float* wf1 = (const float*)d_in[3];
    const float* wf2 = (const float*)d_in[4];
    float* out = (float*)d_out;

    float* ws = (float*)d_ws;
    float* A    = ws;                        // 2,097,152 floats (s1, later s5)
    float* S6   = A + 2097152;               // 524,288 floats
    float* PART = S6 + 524288;               // 4,194,304 floats
    float* WT1  = PART + 4194304;            // 800 floats
    float* WT2  = WT1 + 800;                 // 4608 floats
    unsigned char*  PK1 = (unsigned char*)(WT2 + 4608);          // 1,048,576 B
    unsigned short* PK2 = (unsigned short*)(PK1 + 1048576);      // 1,048,576 u16
    unsigned short* PK3 = (unsigned short*)((char*)PK2 + 2097152); // 262,144 u16
    unsigned int*   PK4 = (unsigned int*)((char*)PK3 + 524288);    // 262,144 u32

    // weight transpose for the SGPR path
    wtrans_k<<<dim3(18), 256, 0, stream>>>(w1, w2, WT1, WT2);
    // L1: pool1+LIF -> A (s1)
    pool1_lif_k<<<dim3(8192), 256, 0, stream>>>(x, A);
    // pack s1 -> PK1
    pack1_k<<<dim3(4096), 256, 0, stream>>>(A, PK1);
    // L2: conv1+LIF+pack -> PK2
    conv1_lif_pack_k<<<dim3(4096), 256, 0, stream>>>(PK1, WT1, PK2);
    // L3: pool2+LIF+pack -> PK3
    pool2pack_k<<<dim3(2048), 256, 0, stream>>>(PK2, PK3);
    // L4: conv2+LIF+pack -> PK4
    conv2_lif_pack_k<<<dim3(2048), 256, 0, stream>>>(PK3, WT2, PK4);
    // L5: pool3+LIF -> A (s5)
    pool3_lif_k<<<dim3(8192), 256, 0, stream>>>(PK4, A);
    // L6: fc1 GEMM -> PART; reduce+LIF -> S6
    fc1_gemm_k      <<<dim3(1024), 256, 0, stream>>>(A, wf1, PART);
    fc1_reduce_lif_k<<<dim3(2048), 256, 0, stream>>>(PART, S6);
    // L7: fc2+LIF+shift -> d_out
    fc2_lif_k<<<dim3(88), 128, 0, stream>>>(S6, wf2, out);
}

// Round 10
// 263.297 us; speedup vs baseline: 1.0298x; 1.0298x over previous
//
#include <hip/hip_runtime.h>

#define TT 128

// LIF constants
#define DECAY_U 0.75f
#define DECAY_V 0.96875f
#define THETA   5120.0f
#define POOLW   88.0f

__device__ __forceinline__ void lif_step(float xt, float& u, float& v, int& refc, float& s) {
    u = __fadd_rn(__fmul_rn(u, DECAY_U), __fmul_rn(xt, 64.0f));
    float vn = __fadd_rn(__fmul_rn(v, DECAY_V), u);
    v = refc ? 0.0f : vn;
    s = (v >= THETA) ? 1.0f : 0.0f;
    if (s > 0.f) { refc = 1; v = 0.f; }
    else         { refc = refc > 0 ? refc - 1 : 0; }
}

// Serial LIF over an LDS column: col[t*stride], t=0..127.
__device__ __forceinline__ void lif_seq_lds(float* col, int stride) {
    float u = 0.f, v = 0.f;
    int refc = 0;
    #pragma unroll 16
    for (int t = 0; t < TT; ++t) {
        float s;
        lif_step(col[t * stride], u, v, refc, s);
        col[t * stride] = s;
    }
}

// ---------------- Weight reorder for GEMM-style convs ----------------
// wT1: [ky][kx*2+c][oc16]  (order ky,kx,c)   800 floats
// wT2: [tap][c][oc32]      (order tap,c)    4608 floats
__global__ void wtrans_k(const float* __restrict__ w1, const float* __restrict__ w2,
                         float* __restrict__ wT1, float* __restrict__ wT2) {
    int i = blockIdx.x * 256 + threadIdx.x;
    if (i < 800) {
        int oc = i & 15;
        int r2 = i >> 4;            // 0..49 = ky*10 + (kx*2+c)
        int ky = r2 / 10;
        int rr = r2 - ky * 10;
        int kx = rr >> 1, c = rr & 1;
        wT1[i] = w1[oc*50 + c*25 + ky*5 + kx];
    }
    if (i < 4608) {
        int oc = i & 31;
        int c  = (i >> 5) & 15;
        int tap = i >> 9;
        wT2[i] = w2[oc*144 + c*9 + tap];
    }
}

// ---------------- L1: sum_pool(x,4)*88 + LIF -> s1 fp32 ----------------
__global__ void pool1_lif_k(const float* __restrict__ x, float* __restrict__ s1) {
    __shared__ float sb[TT][3];
    int t = threadIdx.x & 127, pos = threadIdx.x >> 7;
    int n = blockIdx.x * 2 + pos;
    int px = n & 31, py = (n >> 5) & 31, c = (n >> 10) & 1, b = n >> 11;
    const float* base = x + (size_t)((((b*2 + c)*128 + py*4)*128) + px*4) * 128 + t;
    float s = 0.f;
    #pragma unroll
    for (int dy = 0; dy < 4; ++dy)
        #pragma unroll
        for (int dx = 0; dx < 4; ++dx)
            s += base[(dy*128 + dx) * 128];
    sb[t][pos] = s * POOLW;
    __syncthreads();
    if (threadIdx.x < 2) lif_seq_lds(&sb[0][threadIdx.x], 3);
    __syncthreads();
    s1[(size_t)n * TT + t] = sb[t][pos];
}

// ---------------- pack s1 (2 c bits) -> pk1 [8][1024][128] uint8 ----------------
__global__ void pack1_k(const float* __restrict__ s1, unsigned char* __restrict__ pk1) {
    int id = blockIdx.x * 256 + threadIdx.x;     // 1,048,576
    int t = id & 127;
    int pos = id >> 7;
    int b = pos >> 10, rem = pos & 1023;
    const float* p0 = s1 + (size_t)(b*2) * 131072 + rem * 128 + t;
    unsigned int v = (p0[0] > 0.5f ? 1u : 0u) | (p0[131072] > 0.5f ? 2u : 0u);
    pk1[id] = (unsigned char)v;
}

// ---------------- L2: conv1 as GEMM (16oc x 128t, K=50) + LIF + pack -------------
// block = 1 pos x 128 threads; micro-tile 4oc x 4t; X expanded to LDS floats.
__global__ __launch_bounds__(128) void conv1_gemm_k(const unsigned char* __restrict__ pk1,
                                                    const float* __restrict__ wT1,
                                                    unsigned short* __restrict__ pk2) {
    __shared__ float smem[2176];          // XF[10][132]=1320 | WS[10][16]=160 ; sb[128][17]=2176
    float* XF = smem;
    float* WS = smem + 1320;
    float* sb = smem;
    int tid = threadIdx.x;
    int tg = tid & 31;                    // 4 t each
    int og = tid >> 5;                    // 0..3, 4 oc each
    int pos = blockIdx.x & 1023, b = blockIdx.x >> 10;
    int px = pos & 31, py = pos >> 5;
    const unsigned char* pp = pk1 + (size_t)b * 131072;

    float acc[4][4];
    #pragma unroll
    for (int i = 0; i < 4; ++i)
        #pragma unroll
        for (int j = 0; j < 4; ++j) acc[i][j] = 0.f;

    #pragma unroll
    for (int ky = 0; ky < 5; ++ky) {
        int iy = py + ky - 2;
        __syncthreads();
        // stage W chunk [10][16]
        #pragma unroll
        for (int i = 0; i < 2; ++i) {
            int e = tid + 128*i;
            if (e < 160) WS[e] = wT1[ky*160 + e];
        }
        // stage X chunk: rows r = kx*2+c, XF[r][t] = bit c of neighbor(kx) word at t-1
        #pragma unroll
        for (int i = 0; i < 10; ++i) {
            int e = tid + 128*i;
            int r = e >> 7, t = e & 127;
            int kx = r >> 1, c = r & 1;
            int ix = px + kx - 2;
            bool vs = ((unsigned)iy < 32u) && ((unsigned)ix < 32u);
            const unsigned char* q = pp + (vs ? (iy*32 + ix) * 128 : 0);
            unsigned int w = (vs && t > 0) ? q[t-1] : 0u;
            XF[r*132 + t] = (float)((w >> c) & 1u);
        }
        __syncthreads();
        #pragma unroll
        for (int k = 0; k < 10; ++k) {
            float4 wv = *(const float4*)&WS[k*16 + og*4];
            float4 xv = *(const float4*)&XF[k*132 + tg*4];
            acc[0][0] = fmaf(wv.x, xv.x, acc[0][0]);
            acc[0][1] = fmaf(wv.x, xv.y, acc[0][1]);
            acc[0][2] = fmaf(wv.x, xv.z, acc[0][2]);
            acc[0][3] = fmaf(wv.x, xv.w, acc[0][3]);
            acc[1][0] = fmaf(wv.y, xv.x, acc[1][0]);
            acc[1][1] = fmaf(wv.y, xv.y, acc[1][1]);
            acc[1][2] = fmaf(wv.y, xv.z, acc[1][2]);
            acc[1][3] = fmaf(wv.y, xv.w, acc[1][3]);
            acc[2][0] = fmaf(wv.z, xv.x, acc[2][0]);
            acc[2][1] = fmaf(wv.z, xv.y, acc[2][1]);
            acc[2][2] = fmaf(wv.z, xv.z, acc[2][2]);
            acc[2][3] = fmaf(wv.z, xv.w, acc[2][3]);
            acc[3][0] = fmaf(wv.w, xv.x, acc[3][0]);
            acc[3][1] = fmaf(wv.w, xv.y, acc[3][1]);
            acc[3][2] = fmaf(wv.w, xv.z, acc[3][2]);
            acc[3][3] = fmaf(wv.w, xv.w, acc[3][3]);
        }
    }
    __syncthreads();   // XF reads done; safe to overwrite with sb
    #pragma unroll
    for (int i = 0; i < 4; ++i)
        #pragma unroll
        for (int j = 0; j < 4; ++j)
            sb[(tg*4 + j)*17 + og*4 + i] = acc[i][j];
    __syncthreads();
    if (tid < 16) lif_seq_lds(&sb[tid], 17);
    __syncthreads();
    {
        int t = tid;
        unsigned int w = 0;
        #pragma unroll
        for (int oc = 0; oc < 16; ++oc)
            w |= (sb[t*17 + oc] > 0.5f ? 1u : 0u) << oc;
        pk2[(size_t)b * 131072 + (size_t)pos * 128 + t] = (unsigned short)w;
    }
}

// ---------------- L3: sum_pool(2)*88 (delayed, packed in) + LIF + pack -> pk3 -----
__global__ __launch_bounds__(256) void pool2pack_k(const unsigned short* __restrict__ pk2,
                                                   unsigned short* __restrict__ pk3) {
    __shared__ float sb[TT][17];
    int tid = threadIdx.x;
    int t = tid & 127, half = tid >> 7;
    int pos = blockIdx.x & 255, b = blockIdx.x >> 8;
    int px = pos & 15, py = pos >> 4;
    unsigned int w0 = 0, w1 = 0, w2 = 0, w3 = 0;
    if (t > 0) {
        const unsigned short* q = pk2 + (size_t)b * 131072 + (size_t)(py*2*32 + px*2) * 128 + (t - 1);
        w0 = q[0]; w1 = q[128]; w2 = q[32*128]; w3 = q[33*128];
    }
    #pragma unroll
    for (int j = 0; j < 8; ++j) {
        int c = half*8 + j;
        int cnt = ((w0 >> c) & 1) + ((w1 >> c) & 1) + ((w2 >> c) & 1) + ((w3 >> c) & 1);
        sb[t][c] = POOLW * (float)cnt;
    }
    __syncthreads();
    if (tid < 16) lif_seq_lds(&sb[0][tid], 17);
    __syncthreads();
    if (tid < 128) {
        unsigned int w = 0;
        #pragma unroll
        for (int c = 0; c < 16; ++c)
            w |= (sb[tid][c] > 0.5f ? 1u : 0u) << c;
        pk3[(size_t)b * 32768 + (size_t)pos * 128 + tid] = (unsigned short)w;
    }
}

// ---------------- L4: conv2 as GEMM (32oc x 128t, K=144) + LIF + pack -------------
// block = 1 pos x 256 threads; micro-tile 4oc x 4t; X expanded to LDS floats.
__global__ __launch_bounds__(256) void conv2_gemm_k(const unsigned short* __restrict__ pk3,
                                                    const float* __restrict__ wT2,
                                                    unsigned int* __restrict__ pk4) {
    __shared__ float smem[4224];          // XF[16][132]=2112 | WS[16][32]=512 ; sb[128][33]=4224
    float* XF = smem;
    float* WS = smem + 2112;
    float* sb = smem;
    int tid = threadIdx.x;
    int tg = tid & 31;                    // 4 t each
    int og = tid >> 5;                    // 0..7, 4 oc each
    int pos = blockIdx.x & 255, b = blockIdx.x >> 8;
    int px = pos & 15, py = pos >> 4;
    const unsigned short* pp = pk3 + (size_t)b * 32768;

    float acc[4][4];
    #pragma unroll
    for (int i = 0; i < 4; ++i)
        #pragma unroll
        for (int j = 0; j < 4; ++j) acc[i][j] = 0.f;

    #pragma unroll
    for (int tap = 0; tap < 9; ++tap) {
        int ky = tap / 3, kx = tap % 3;
        int iy = py + ky - 1, ix = px + kx - 1;
        bool vs = ((unsigned)iy < 16u) && ((unsigned)ix < 16u);
        const unsigned short* q = pp + (vs ? (iy*16 + ix) * 128 : 0);
        __syncthreads();
        // stage W chunk [16][32]
        #pragma unroll
        for (int i = 0; i < 2; ++i) {
            int e = tid + 256*i;
            WS[e] = wT2[tap*512 + e];
        }
        // stage X chunk: XF[c][t] = bit c of word at t-1
        #pragma unroll
        for (int i = 0; i < 8; ++i) {
            int e = tid + 256*i;
            int c = e >> 7, t = e & 127;
            unsigned int w = (vs && t > 0) ? q[t-1] : 0u;
            XF[c*132 + t] = (float)((w >> c) & 1u);
        }
        __syncthreads();
        #pragma unroll
        for (int k = 0; k < 16; ++k) {
            float4 wv = *(const float4*)&WS[k*32 + og*4];
            float4 xv = *(const float4*)&XF[k*132 + tg*4];
            acc[0][0] = fmaf(wv.x, xv.x, acc[0][0]);
            acc[0][1] = fmaf(wv.x, xv.y, acc[0][1]);
            acc[0][2] = fmaf(wv.x, xv.z, acc[0][2]);
            acc[0][3] = fmaf(wv.x, xv.w, acc[0][3]);
            acc[1][0] = fmaf(wv.y, xv.x, acc[1][0]);
            acc[1][1] = fmaf(wv.y, xv.y, acc[1][1]);
            acc[1][2] = fmaf(wv.y, xv.z, acc[1][2]);
            acc[1][3] = fmaf(wv.y, xv.w, acc[1][3]);
            acc[2][0] = fmaf(wv.z, xv.x, acc[2][0]);
            acc[2][1] = fmaf(wv.z, xv.y, acc[2][1]);
            acc[2][2] = fmaf(wv.z, xv.z, acc[2][2]);
            acc[2][3] = fmaf(wv.z, xv.w, acc[2][3]);
            acc[3][0] = fmaf(wv.w, xv.x, acc[3][0]);
            acc[3][1] = fmaf(wv.w, xv.y, acc[3][1]);
            acc[3][2] = fmaf(wv.w, xv.z, acc[3][2]);
            acc[3][3] = fmaf(wv.w, xv.w, acc[3][3]);
        }
    }
    __syncthreads();   // XF reads done; safe to overwrite with sb
    #pragma unroll
    for (int i = 0; i < 4; ++i)
        #pragma unroll
        for (int j = 0; j < 4; ++j)
            sb[(tg*4 + j)*33 + og*4 + i] = acc[i][j];
    __syncthreads();
    if (tid < 32) lif_seq_lds(&sb[tid], 33);
    __syncthreads();
    if (tid < 128) {
        unsigned int w = 0;
        #pragma unroll
        for (int oc = 0; oc < 32; ++oc)
            w |= (sb[tid*33 + oc] > 0.5f ? 1u : 0u) << oc;
        pk4[(size_t)b * 32768 + (size_t)pos * 128 + tid] = w;
    }
}

// ---------------- L5: sum_pool(2)*88 (delayed, packed in) + LIF -> s5 fp32 --------
__global__ void pool3_lif_k(const unsigned int* __restrict__ pk4, float* __restrict__ s5) {
    __shared__ float sb[TT][3];
    int t = threadIdx.x & 127, pos = threadIdx.x >> 7;
    int n = blockIdx.x * 2 + pos;
    int px = n & 7, py = (n >> 3) & 7, c = (n >> 6) & 31, b = n >> 11;
    float acc = 0.f;
    if (t > 0) {
        const unsigned int* q = pk4 + (size_t)b * 32768 + (size_t)(py*2*16 + px*2) * 128 + (t - 1);
        unsigned int w0 = q[0], w1 = q[128], w2 = q[16*128], w3 = q[17*128];
        int cnt = ((w0 >> c) & 1) + ((w1 >> c) & 1) + ((w2 >> c) & 1) + ((w3 >> c) & 1);
        acc = POOLW * (float)cnt;
    }
    sb[t][pos] = acc;
    __syncthreads();
    if (threadIdx.x < 2) lif_seq_lds(&sb[0][threadIdx.x], 3);
    __syncthreads();
    s5[(size_t)n * TT + t] = sb[t][pos];
}

// ---------------- L6: fc1 tiled K-split GEMM ----------------
__global__ __launch_bounds__(256) void fc1_gemm_k(const float* __restrict__ s5,
                                                  const float* __restrict__ wf1,
                                                  float* __restrict__ part) {
    __shared__ float WT[64][68];
    __shared__ float ST[64][68];
    int bid = blockIdx.x;
    int kc = bid & 7;
    int ot = (bid >> 3) & 7;
    int tt = (bid >> 6) & 1;
    int b  = bid >> 7;
    int tid = threadIdx.x;
    int oo = tid >> 4;
    int to = tid & 15;

    const float* wbase = wf1 + (size_t)(ot*64) * 2048 + kc*256;
    const float* sbase = s5 + (size_t)b * 262144 + (size_t)(kc*256) * 128;

    float acc[4][4];
    #pragma unroll
    for (int i = 0; i < 4; ++i)
        #pragma unroll
        for (int j = 0; j < 4; ++j) acc[i][j] = 0.f;

    for (int ks = 0; ks < 4; ++ks) {
        __syncthreads();
        #pragma unroll
        for (int i = 0; i < 16; ++i) {
            int e = tid + 256*i;
            int o = e >> 6, f = e & 63;
            WT[f][o] = wbase[(size_t)o * 2048 + ks*64 + f];
        }
        #pragma unroll
        for (int i = 0; i < 16; ++i) {
            int e = tid + 256*i;
            int f = e >> 6, tl = e & 63;
            int tsrc = tt*64 + tl - 1;
            ST[f][tl] = (tsrc < 0) ? 0.f : sbase[(size_t)f * 128 + ks*64*128 + tsrc];
        }
        __syncthreads();
        #pragma unroll 4
        for (int k = 0; k < 64; ++k) {
            float4 a = *(const float4*)&WT[k][oo*4];
            float4 s = *(const float4*)&ST[k][to*4];
            acc[0][0] = fmaf(a.x, s.x, acc[0][0]);
            acc[0][1] = fmaf(a.x, s.y, acc[0][1]);
            acc[0][2] = fmaf(a.x, s.z, acc[0][2]);
            acc[0][3] = fmaf(a.x, s.w, acc[0][3]);
            acc[1][0] = fmaf(a.y, s.x, acc[1][0]);
            acc[1][1] = fmaf(a.y, s.y, acc[1][1]);
            acc[1][2] = fmaf(a.y, s.z, acc[1][2]);
            acc[1][3] = fmaf(a.y, s.w, acc[1][3]);
            acc[2][0] = fmaf(a.z, s.x, acc[2][0]);
            acc[2][1] = fmaf(a.z, s.y, acc[2][1]);
            acc[2][2] = fmaf(a.z, s.z, acc[2][2]);
            acc[2][3] = fmaf(a.z, s.w, acc[2][3]);
            acc[3][0] = fmaf(a.w, s.x, acc[3][0]);
            acc[3][1] = fmaf(a.w, s.y, acc[3][1]);
            acc[3][2] = fmaf(a.w, s.z, acc[3][2]);
            acc[3][3] = fmaf(a.w, s.w, acc[3][3]);
        }
    }
    float* pb = part + (size_t)kc * 524288 + (size_t)b * 65536
              + (size_t)(ot*64 + oo*4) * 128 + tt*64 + to*4;
    #pragma unroll
    for (int i = 0; i < 4; ++i)
        #pragma unroll
        for (int j = 0; j < 4; ++j)
            pb[(size_t)i * 128 + j] = acc[i][j];
}

// ---------------- L6b: sum 8 K-chunks (fixed order) + LIF -> s6 ----------------
__global__ void fc1_reduce_lif_k(const float* __restrict__ part, float* __restrict__ s6) {
    __shared__ float sb[TT][3];
    int t = threadIdx.x & 127, pos = threadIdx.x >> 7;
    int n = blockIdx.x * 2 + pos;
    float s = 0.f;
    #pragma unroll
    for (int kc = 0; kc < 8; ++kc)
        s += part[(size_t)kc * 524288 + (size_t)n * 128 + t];
    sb[t][pos] = s;
    __syncthreads();
    if (threadIdx.x < 2) lif_seq_lds(&sb[0][threadIdx.x], 3);
    __syncthreads();
    s6[(size_t)n * TT + t] = sb[t][pos];
}

// ---------------- L7: fc2 512->11 (delayed) + LIF + final shift -> out ----------
__global__ void fc2_lif_k(const float* __restrict__ s6, const float* __restrict__ wf2,
                          float* __restrict__ out) {
    __shared__ float sb[TT];
    int t = threadIdx.x;
    int o = blockIdx.x % 11, b = blockIdx.x / 11;
    float acc = 0.f;
    if (t > 0) {
        const float* sp = s6 + (size_t)b * 65536 + (t - 1);
        const float* wp = wf2 + o * 512;
        for (int f = 0; f < 512; f += 4) {
            float4 w = *(const float4*)&wp[f];
            acc = fmaf(w.x, sp[(size_t)f * 128], acc);
            acc = fmaf(w.y, sp[(size_t)(f+1) * 128], acc);
            acc = fmaf(w.z, sp[(size_t)(f+2) * 128], acc);
            acc = fmaf(w.w, sp[(size_t)(f+3) * 128], acc);
        }
    }
    sb[t] = acc;
    __syncthreads();
    if (t == 0) lif_seq_lds(sb, 1);
    __syncthreads();
    float* q = out + (size_t)(b*11 + o) * TT;
    if (t == 0) q[0] = 0.f;
    if (t < TT - 1) q[t + 1] = sb[t];
}

extern "C" void kernel_launch(void* const* d_in, const int* in_sizes, int n_in,
                              void* d_out, int out_size, void* d_ws, size_t ws_size,
                              hipStream_t stream) {
    const float* x   = (const float*)d_in[0];
    const float* w1  = (const float*)d_in[1];
    const float* w2  = (const float*)d_in[2];
    const float* wf1 = (const float*)d_in[3];
    const float* wf2 = (const float*)d_in[4];
    float* out = (float*)d_out;

    float* ws = (float*)d_ws;
    float* A    = ws;                        // 2,097,152 floats (s1, later s5)
    float* S6   = A + 2097152;               // 524,288 floats
    float* PART = S6 + 524288;               // 4,194,304 floats
    float* WT1  = PART + 4194304;            // 800 floats
    float* WT2  = WT1 + 800;                 // 4608 floats
    unsigned char*  PK1 = (unsigned char*)(WT2 + 4608);            // 1,048,576 B
    unsigned short* PK2 = (unsigned short*)(PK1 + 1048576);        // 1,048,576 u16
    unsigned short* PK3 = (unsigned short*)((char*)PK2 + 2097152); // 262,144 u16
    unsigned int*   PK4 = (unsigned int*)((char*)PK3 + 524288);    // 262,144 u32

    // weight reorder for GEMM convs
    wtrans_k<<<dim3(18), 256, 0, stream>>>(w1, w2, WT1, WT2);
    // L1: pool1+LIF -> A (s1)
    pool1_lif_k<<<dim3(8192), 256, 0, stream>>>(x, A);
    // pack s1 -> PK1
    pack1_k<<<dim3(4096), 256, 0, stream>>>(A, PK1);
    // L2: conv1 GEMM +LIF+pack -> PK2
    conv1_gemm_k<<<dim3(8192), 128, 0, stream>>>(PK1, WT1, PK2);
    // L3: pool2+LIF+pack -> PK3
    pool2pack_k<<<dim3(2048), 256, 0, stream>>>(PK2, PK3);
    // L4: conv2 GEMM +LIF+pack -> PK4
    conv2_gemm_k<<<dim3(2048), 256, 0, stream>>>(PK3, WT2, PK4);
    // L5: pool3+LIF -> A (s5)
    pool3_lif_k<<<dim3(8192), 256, 0, stream>>>(PK4, A);
    // L6: fc1 GEMM -> PART; reduce+LIF -> S6
    fc1_gemm_k      <<<dim3(1024), 256, 0, stream>>>(A, wf1, PART);
    fc1_reduce_lif_k<<<dim3(2048), 256, 0, stream>>>(PART, S6);
    // L7: fc2+LIF+shift -> d_out
    fc2_lif_k<<<dim3(88), 128, 0, stream>>>(S6, wf2, out);
}

// Round 11
// 207.683 us; speedup vs baseline: 1.3055x; 1.2678x over previous
//
#include <hip/hip_runtime.h>

#define TT 128

// LIF constants
#define DECAY_U 0.75f
#define DECAY_V 0.96875f
#define THETA   5120.0f
#define POOLW   88.0f

__device__ __forceinline__ void lif_step(float xt, float& u, float& v, int& refc, float& s) {
    u = __fadd_rn(__fmul_rn(u, DECAY_U), __fmul_rn(xt, 64.0f));
    float vn = __fadd_rn(__fmul_rn(v, DECAY_V), u);
    v = refc ? 0.0f : vn;
    s = (v >= THETA) ? 1.0f : 0.0f;
    if (s > 0.f) { refc = 1; v = 0.f; }
    else         { refc = refc > 0 ? refc - 1 : 0; }
}

// Serial LIF over an LDS column: col[t*stride], t=0..127.
__device__ __forceinline__ void lif_seq_lds(float* col, int stride) {
    float u = 0.f, v = 0.f;
    int refc = 0;
    #pragma unroll 16
    for (int t = 0; t < TT; ++t) {
        float s;
        lif_step(col[t * stride], u, v, refc, s);
        col[t * stride] = s;
    }
}

// ---------------- Weight reorder ----------------
// wT1: [ky][kx*2+c][oc16]  800 floats  |  wT2: [tap][c][oc32]  4608 floats
__global__ void wtrans_k(const float* __restrict__ w1, const float* __restrict__ w2,
                         float* __restrict__ wT1, float* __restrict__ wT2) {
    int i = blockIdx.x * 256 + threadIdx.x;
    if (i < 800) {
        int oc = i & 15;
        int r2 = i >> 4;            // ky*10 + (kx*2+c)
        int ky = r2 / 10;
        int rr = r2 - ky * 10;
        int kx = rr >> 1, c = rr & 1;
        wT1[i] = w1[oc*50 + c*25 + ky*5 + kx];
    }
    if (i < 4608) {
        int oc = i & 31;
        int c  = (i >> 5) & 15;
        int tap = i >> 9;
        wT2[i] = w2[oc*144 + c*9 + tap];
    }
}

// ---------------- L1: sum_pool(x,4)*88 + LIF + pack -> pk1 u8 ----------------
// block = 1 pos x (2c x 128t); writes packed u8 directly.
__global__ void pool1_lif_k(const float* __restrict__ x, unsigned char* __restrict__ pk1) {
    __shared__ float sb[TT][3];
    int t = threadIdx.x & 127, c = threadIdx.x >> 7;
    int pos = blockIdx.x & 1023, b = blockIdx.x >> 10;
    int px = pos & 31, py = pos >> 5;
    const float* base = x + (size_t)((((b*2 + c)*128 + py*4)*128) + px*4) * 128 + t;
    float s = 0.f;
    #pragma unroll
    for (int dy = 0; dy < 4; ++dy)
        #pragma unroll
        for (int dx = 0; dx < 4; ++dx)
            s += base[(dy*128 + dx) * 128];
    sb[t][c] = s * POOLW;
    __syncthreads();
    if (threadIdx.x < 2) lif_seq_lds(&sb[0][threadIdx.x], 3);
    __syncthreads();
    if (threadIdx.x < 128) {
        unsigned int v = (sb[t][0] > 0.5f ? 1u : 0u) | (sb[t][1] > 0.5f ? 2u : 0u);
        pk1[(size_t)b * 131072 + (size_t)pos * 128 + t] = (unsigned char)v;
    }
}

// ---------------- L2: conv1 single-stage GEMM (2 pos/block) + LIF + pack ----------
// 256 thr: og=tid>>6 (4 oc), pos=(tid>>5)&1, tg=tid&31 (4 t). K=50 staged once.
__global__ __launch_bounds__(256) void conv1_gemm_k(const unsigned char* __restrict__ pk1,
                                                    const float* __restrict__ wT1,
                                                    unsigned short* __restrict__ pk2) {
    __shared__ float smem[4760];            // WS[800] | XN[5*6*132=3960] ; sb[128*33=4224] aliases
    float* WS = smem;
    unsigned int* XN = (unsigned int*)(smem + 800);
    float* sb = smem;
    int tid = threadIdx.x;
    int ppair = blockIdx.x & 511, b = blockIdx.x >> 9;
    int py = ppair >> 4, px0 = (ppair & 15) * 2;
    const unsigned char* pp = pk1 + (size_t)b * 131072;

    // stage W (800) and packed neighborhood XN[5 iy][6 xc][128 t]
    #pragma unroll
    for (int i = 0; i < 4; ++i) {
        int e = tid + 256*i;
        if (e < 800) WS[e] = wT1[e];
    }
    #pragma unroll
    for (int i = 0; i < 15; ++i) {
        int e = tid + 256*i;                 // 3840 entries
        int row = e >> 7, t = e & 127;
        int ky = row / 6, xc = row - ky*6;
        int iy = py + ky - 2, ix = px0 + xc - 2;
        bool vs = ((unsigned)iy < 32u) && ((unsigned)ix < 32u) && (t > 0);
        XN[row*132 + t] = vs ? (unsigned int)pp[(iy*32 + ix)*128 + t - 1] : 0u;
    }
    __syncthreads();

    int tg = tid & 31;
    int pos = (tid >> 5) & 1;
    int og = tid >> 6;                       // wave-uniform
    float acc[4][4];
    #pragma unroll
    for (int i = 0; i < 4; ++i)
        #pragma unroll
        for (int j = 0; j < 4; ++j) acc[i][j] = 0.f;

    #pragma unroll
    for (int ky = 0; ky < 5; ++ky) {
        #pragma unroll
        for (int kx = 0; kx < 5; ++kx) {
            uint4 xw = *(const uint4*)&XN[(ky*6 + kx + pos)*132 + tg*4];
            #pragma unroll
            for (int c = 0; c < 2; ++c) {
                float4 wv = *(const float4*)&WS[(ky*10 + kx*2 + c)*16 + og*4];
                float x0 = (float)((xw.x >> c) & 1u);
                float x1 = (float)((xw.y >> c) & 1u);
                float x2 = (float)((xw.z >> c) & 1u);
                float x3 = (float)((xw.w >> c) & 1u);
                acc[0][0] = fmaf(wv.x, x0, acc[0][0]);
                acc[0][1] = fmaf(wv.x, x1, acc[0][1]);
                acc[0][2] = fmaf(wv.x, x2, acc[0][2]);
                acc[0][3] = fmaf(wv.x, x3, acc[0][3]);
                acc[1][0] = fmaf(wv.y, x0, acc[1][0]);
                acc[1][1] = fmaf(wv.y, x1, acc[1][1]);
                acc[1][2] = fmaf(wv.y, x2, acc[1][2]);
                acc[1][3] = fmaf(wv.y, x3, acc[1][3]);
                acc[2][0] = fmaf(wv.z, x0, acc[2][0]);
                acc[2][1] = fmaf(wv.z, x1, acc[2][1]);
                acc[2][2] = fmaf(wv.z, x2, acc[2][2]);
                acc[2][3] = fmaf(wv.z, x3, acc[2][3]);
                acc[3][0] = fmaf(wv.w, x0, acc[3][0]);
                acc[3][1] = fmaf(wv.w, x1, acc[3][1]);
                acc[3][2] = fmaf(wv.w, x2, acc[3][2]);
                acc[3][3] = fmaf(wv.w, x3, acc[3][3]);
            }
        }
    }
    __syncthreads();   // XN/WS reads done; reuse smem as sb
    // sb[t][col], col = oc*2 + pos (32 cols, stride 33)
    #pragma unroll
    for (int i = 0; i < 4; ++i)
        #pragma unroll
        for (int j = 0; j < 4; ++j)
            sb[(tg*4 + j)*33 + (og*4 + i)*2 + pos] = acc[i][j];
    __syncthreads();
    if (tid < 32) lif_seq_lds(&sb[tid], 33);
    __syncthreads();
    if (tid < 128) {
        int t = tid;
        #pragma unroll
        for (int p2 = 0; p2 < 2; ++p2) {
            unsigned int w = 0;
            #pragma unroll
            for (int oc = 0; oc < 16; ++oc)
                w |= (sb[t*33 + oc*2 + p2] > 0.5f ? 1u : 0u) << oc;
            int pos_out = py*32 + px0 + p2;
            pk2[(size_t)b * 131072 + (size_t)pos_out * 128 + t] = (unsigned short)w;
        }
    }
}

// ---------------- L3: sum_pool(2)*88 (delayed, packed in) + LIF + pack -> pk3 -----
__global__ __launch_bounds__(256) void pool2pack_k(const unsigned short* __restrict__ pk2,
                                                   unsigned short* __restrict__ pk3) {
    __shared__ float sb[TT][17];
    int tid = threadIdx.x;
    int t = tid & 127, half = tid >> 7;
    int pos = blockIdx.x & 255, b = blockIdx.x >> 8;
    int px = pos & 15, py = pos >> 4;
    unsigned int w0 = 0, w1 = 0, w2 = 0, w3 = 0;
    if (t > 0) {
        const unsigned short* q = pk2 + (size_t)b * 131072 + (size_t)(py*2*32 + px*2) * 128 + (t - 1);
        w0 = q[0]; w1 = q[128]; w2 = q[32*128]; w3 = q[33*128];
    }
    #pragma unroll
    for (int j = 0; j < 8; ++j) {
        int c = half*8 + j;
        int cnt = ((w0 >> c) & 1) + ((w1 >> c) & 1) + ((w2 >> c) & 1) + ((w3 >> c) & 1);
        sb[t][c] = POOLW * (float)cnt;
    }
    __syncthreads();
    if (tid < 16) lif_seq_lds(&sb[0][tid], 17);
    __syncthreads();
    if (tid < 128) {
        unsigned int w = 0;
        #pragma unroll
        for (int c = 0; c < 16; ++c)
            w |= (sb[tid][c] > 0.5f ? 1u : 0u) << c;
        pk3[(size_t)b * 32768 + (size_t)pos * 128 + tid] = (unsigned short)w;
    }
}

// ---------------- L4: conv2 single-stage GEMM + LIF + pack -> pk4 ----------------
// 256 thr: og=tid>>5 (4 oc of 32), tg=tid&31 (4 t). K=144 staged once (packed X).
__global__ __launch_bounds__(256) void conv2_gemm_k(const unsigned short* __restrict__ pk3,
                                                    const float* __restrict__ wT2,
                                                    unsigned int* __restrict__ pk4) {
    __shared__ float smem[5796];            // WS[4608] | XL[9*132=1188] ; sb[128*33] aliases
    float* WS = smem;
    unsigned int* XL = (unsigned int*)(smem + 4608);
    float* sb = smem;
    int tid = threadIdx.x;
    int pos = blockIdx.x & 255, b = blockIdx.x >> 8;
    int px = pos & 15, py = pos >> 4;
    const unsigned short* pp = pk3 + (size_t)b * 32768;

    #pragma unroll
    for (int i = 0; i < 18; ++i)
        WS[tid + 256*i] = wT2[tid + 256*i];
    #pragma unroll
    for (int i = 0; i < 5; ++i) {
        int e = tid + 256*i;
        if (e < 1152) {
            int tap = e >> 7, t = e & 127;
            int ky = tap / 3, kx = tap - ky*3;
            int iy = py + ky - 1, ix = px + kx - 1;
            bool vs = ((unsigned)iy < 16u) && ((unsigned)ix < 16u) && (t > 0);
            XL[tap*132 + t] = vs ? (unsigned int)pp[(iy*16 + ix)*128 + t - 1] : 0u;
        }
    }
    __syncthreads();

    int tg = tid & 31;
    int og = tid >> 5;
    float acc[4][4];
    #pragma unroll
    for (int i = 0; i < 4; ++i)
        #pragma unroll
        for (int j = 0; j < 4; ++j) acc[i][j] = 0.f;

    #pragma unroll
    for (int tap = 0; tap < 9; ++tap) {
        uint4 xw = *(const uint4*)&XL[tap*132 + tg*4];
        #pragma unroll
        for (int c = 0; c < 16; ++c) {
            float4 wv = *(const float4*)&WS[tap*512 + c*32 + og*4];
            float x0 = (float)((xw.x >> c) & 1u);
            float x1 = (float)((xw.y >> c) & 1u);
            float x2 = (float)((xw.z >> c) & 1u);
            float x3 = (float)((xw.w >> c) & 1u);
            acc[0][0] = fmaf(wv.x, x0, acc[0][0]);
            acc[0][1] = fmaf(wv.x, x1, acc[0][1]);
            acc[0][2] = fmaf(wv.x, x2, acc[0][2]);
            acc[0][3] = fmaf(wv.x, x3, acc[0][3]);
            acc[1][0] = fmaf(wv.y, x0, acc[1][0]);
            acc[1][1] = fmaf(wv.y, x1, acc[1][1]);
            acc[1][2] = fmaf(wv.y, x2, acc[1][2]);
            acc[1][3] = fmaf(wv.y, x3, acc[1][3]);
            acc[2][0] = fmaf(wv.z, x0, acc[2][0]);
            acc[2][1] = fmaf(wv.z, x1, acc[2][1]);
            acc[2][2] = fmaf(wv.z, x2, acc[2][2]);
            acc[2][3] = fmaf(wv.z, x3, acc[2][3]);
            acc[3][0] = fmaf(wv.w, x0, acc[3][0]);
            acc[3][1] = fmaf(wv.w, x1, acc[3][1]);
            acc[3][2] = fmaf(wv.w, x2, acc[3][2]);
            acc[3][3] = fmaf(wv.w, x3, acc[3][3]);
        }
    }
    __syncthreads();   // XL/WS reads done; reuse smem as sb
    #pragma unroll
    for (int i = 0; i < 4; ++i)
        #pragma unroll
        for (int j = 0; j < 4; ++j)
            sb[(tg*4 + j)*33 + og*4 + i] = acc[i][j];
    __syncthreads();
    if (tid < 32) lif_seq_lds(&sb[tid], 33);
    __syncthreads();
    if (tid < 128) {
        unsigned int w = 0;
        #pragma unroll
        for (int oc = 0; oc < 32; ++oc)
            w |= (sb[tid*33 + oc] > 0.5f ? 1u : 0u) << oc;
        pk4[(size_t)b * 32768 + (size_t)pos * 128 + tid] = w;
    }
}

// ---------------- L5: sum_pool(2)*88 (delayed, packed in) + LIF -> s5 fp32 --------
__global__ void pool3_lif_k(const unsigned int* __restrict__ pk4, float* __restrict__ s5) {
    __shared__ float sb[TT][3];
    int t = threadIdx.x & 127, pos = threadIdx.x >> 7;
    int n = blockIdx.x * 2 + pos;
    int px = n & 7, py = (n >> 3) & 7, c = (n >> 6) & 31, b = n >> 11;
    float acc = 0.f;
    if (t > 0) {
        const unsigned int* q = pk4 + (size_t)b * 32768 + (size_t)(py*2*16 + px*2) * 128 + (t - 1);
        unsigned int w0 = q[0], w1 = q[128], w2 = q[16*128], w3 = q[17*128];
        int cnt = ((w0 >> c) & 1) + ((w1 >> c) & 1) + ((w2 >> c) & 1) + ((w3 >> c) & 1);
        acc = POOLW * (float)cnt;
    }
    sb[t][pos] = acc;
    __syncthreads();
    if (threadIdx.x < 2) lif_seq_lds(&sb[0][threadIdx.x], 3);
    __syncthreads();
    s5[(size_t)n * TT + t] = sb[t][pos];
}

// ---------------- L6: fc1 tiled K-split GEMM ----------------
__global__ __launch_bounds__(256) void fc1_gemm_k(const float* __restrict__ s5,
                                                  const float* __restrict__ wf1,
                                                  float* __restrict__ part) {
    __shared__ float WT[64][68];
    __shared__ float ST[64][68];
    int bid = blockIdx.x;
    int kc = bid & 7;
    int ot = (bid >> 3) & 7;
    int tt = (bid >> 6) & 1;
    int b  = bid >> 7;
    int tid = threadIdx.x;
    int oo = tid >> 4;
    int to = tid & 15;

    const float* wbase = wf1 + (size_t)(ot*64) * 2048 + kc*256;
    const float* sbase = s5 + (size_t)b * 262144 + (size_t)(kc*256) * 128;

    float acc[4][4];
    #pragma unroll
    for (int i = 0; i < 4; ++i)
        #pragma unroll
        for (int j = 0; j < 4; ++j) acc[i][j] = 0.f;

    for (int ks = 0; ks < 4; ++ks) {
        __syncthreads();
        #pragma unroll
        for (int i = 0; i < 16; ++i) {
            int e = tid + 256*i;
            int o = e >> 6, f = e & 63;
            WT[f][o] = wbase[(size_t)o * 2048 + ks*64 + f];
        }
        #pragma unroll
        for (int i = 0; i < 16; ++i) {
            int e = tid + 256*i;
            int f = e >> 6, tl = e & 63;
            int tsrc = tt*64 + tl - 1;
            ST[f][tl] = (tsrc < 0) ? 0.f : sbase[(size_t)f * 128 + ks*64*128 + tsrc];
        }
        __syncthreads();
        #pragma unroll 4
        for (int k = 0; k < 64; ++k) {
            float4 a = *(const float4*)&WT[k][oo*4];
            float4 s = *(const float4*)&ST[k][to*4];
            acc[0][0] = fmaf(a.x, s.x, acc[0][0]);
            acc[0][1] = fmaf(a.x, s.y, acc[0][1]);
            acc[0][2] = fmaf(a.x, s.z, acc[0][2]);
            acc[0][3] = fmaf(a.x, s.w, acc[0][3]);
            acc[1][0] = fmaf(a.y, s.x, acc[1][0]);
            acc[1][1] = fmaf(a.y, s.y, acc[1][1]);
            acc[1][2] = fmaf(a.y, s.z, acc[1][2]);
            acc[1][3] = fmaf(a.y, s.w, acc[1][3]);
            acc[2][0] = fmaf(a.z, s.x, acc[2][0]);
            acc[2][1] = fmaf(a.z, s.y, acc[2][1]);
            acc[2][2] = fmaf(a.z, s.z, acc[2][2]);
            acc[2][3] = fmaf(a.z, s.w, acc[2][3]);
            acc[3][0] = fmaf(a.w, s.x, acc[3][0]);
            acc[3][1] = fmaf(a.w, s.y, acc[3][1]);
            acc[3][2] = fmaf(a.w, s.z, acc[3][2]);
            acc[3][3] = fmaf(a.w, s.w, acc[3][3]);
        }
    }
    float* pb = part + (size_t)kc * 524288 + (size_t)b * 65536
              + (size_t)(ot*64 + oo*4) * 128 + tt*64 + to*4;
    #pragma unroll
    for (int i = 0; i < 4; ++i)
        #pragma unroll
        for (int j = 0; j < 4; ++j)
            pb[(size_t)i * 128 + j] = acc[i][j];
}

// ---------------- L6b: sum 8 K-chunks (fixed order) + LIF -> s6 ----------------
__global__ void fc1_reduce_lif_k(const float* __restrict__ part, float* __restrict__ s6) {
    __shared__ float sb[TT][3];
    int t = threadIdx.x & 127, pos = threadIdx.x >> 7;
    int n = blockIdx.x * 2 + pos;
    float s = 0.f;
    #pragma unroll
    for (int kc = 0; kc < 8; ++kc)
        s += part[(size_t)kc * 524288 + (size_t)n * 128 + t];
    sb[t][pos] = s;
    __syncthreads();
    if (threadIdx.x < 2) lif_seq_lds(&sb[0][threadIdx.x], 3);
    __syncthreads();
    s6[(size_t)n * TT + t] = sb[t][pos];
}

// ---------------- L7: fc2 512->11 (delayed) + LIF + final shift -> out ----------
__global__ void fc2_lif_k(const float* __restrict__ s6, const float* __restrict__ wf2,
                          float* __restrict__ out) {
    __shared__ float sb[TT];
    int t = threadIdx.x;
    int o = blockIdx.x % 11, b = blockIdx.x / 11;
    float acc = 0.f;
    if (t > 0) {
        const float* sp = s6 + (size_t)b * 65536 + (t - 1);
        const float* wp = wf2 + o * 512;
        for (int f = 0; f < 512; f += 4) {
            float4 w = *(const float4*)&wp[f];
            acc = fmaf(w.x, sp[(size_t)f * 128], acc);
            acc = fmaf(w.y, sp[(size_t)(f+1) * 128], acc);
            acc = fmaf(w.z, sp[(size_t)(f+2) * 128], acc);
            acc = fmaf(w.w, sp[(size_t)(f+3) * 128], acc);
        }
    }
    sb[t] = acc;
    __syncthreads();
    if (t == 0) lif_seq_lds(sb, 1);
    __syncthreads();
    float* q = out + (size_t)(b*11 + o) * TT;
    if (t == 0) q[0] = 0.f;
    if (t < TT - 1) q[t + 1] = sb[t];
}

extern "C" void kernel_launch(void* const* d_in, const int* in_sizes, int n_in,
                              void* d_out, int out_size, void* d_ws, size_t ws_size,
                              hipStream_t stream) {
    const float* x   = (const float*)d_in[0];
    const float* w1  = (const float*)d_in[1];
    const float* w2  = (const float*)d_in[2];
    const float* wf1 = (const float*)d_in[3];
    const float* wf2 = (const float*)d_in[4];
    float* out = (float*)d_out;

    float* ws = (float*)d_ws;
    float* A    = ws;                        // 2,097,152 floats (s5)
    float* S6   = A + 2097152;               // 524,288 floats
    float* PART = S6 + 524288;               // 4,194,304 floats
    float* WT1  = PART + 4194304;            // 800 floats
    float* WT2  = WT1 + 800;                 // 4608 floats
    unsigned char*  PK1 = (unsigned char*)(WT2 + 4608);            // 1,048,576 B
    unsigned short* PK2 = (unsigned short*)(PK1 + 1048576);        // 1,048,576 u16
    unsigned short* PK3 = (unsigned short*)((char*)PK2 + 2097152); // 262,144 u16
    unsigned int*   PK4 = (unsigned int*)((char*)PK3 + 524288);    // 262,144 u32

    // weight reorder for GEMM convs
    wtrans_k<<<dim3(18), 256, 0, stream>>>(w1, w2, WT1, WT2);
    // L1: pool1+LIF+pack -> PK1
    pool1_lif_k<<<dim3(8192), 256, 0, stream>>>(x, PK1);
    // L2: conv1 single-stage GEMM +LIF+pack -> PK2 (2 pos/block)
    conv1_gemm_k<<<dim3(4096), 256, 0, stream>>>(PK1, WT1, PK2);
    // L3: pool2+LIF+pack -> PK3
    pool2pack_k<<<dim3(2048), 256, 0, stream>>>(PK2, PK3);
    // L4: conv2 single-stage GEMM +LIF+pack -> PK4
    conv2_gemm_k<<<dim3(2048), 256, 0, stream>>>(PK3, WT2, PK4);
    // L5: pool3+LIF -> A (s5)
    pool3_lif_k<<<dim3(8192), 256, 0, stream>>>(PK4, A);
    // L6: fc1 GEMM -> PART; reduce+LIF -> S6
    fc1_gemm_k      <<<dim3(1024), 256, 0, stream>>>(A, wf1, PART);
    fc1_reduce_lif_k<<<dim3(2048), 256, 0, stream>>>(PART, S6);
    // L7: fc2+LIF+shift -> d_out
    fc2_lif_k<<<dim3(88), 128, 0, stream>>>(S6, wf2, out);
}